// Round 1
// 501.530 us; speedup vs baseline: 1.1433x; 1.1433x over previous
//
#include <hip/hip_runtime.h>
#include <math.h>

#define NEGV -10000000.0f

constexpr int B_ = 8, T_ = 16;
constexpr int QALL = 256, QRES = 128, QARG = 192;
constexpr int STATE = 256, VOCAB = 10000;
constexpr int WT = 128;
constexpr int NWT = (VOCAB + WT - 1) / WT;   // 79

// ---- workspace layout (units of 4 bytes) ----
constexpr size_t OFF_CHART = 0;                                    // chart[ell][s][b][a]
constexpr size_t CHART_SZ  = (size_t)T_ * T_ * B_ * QALL;          // 524288
constexpr size_t OFF_EGR   = OFF_CHART + CHART_SZ;                 // exp(G_rarg) [j][r]
constexpr size_t OFF_EGL   = OFF_EGR + (size_t)QARG * QRES;        // exp(G_larg) [j][r]
constexpr size_t OFF_LF    = OFF_EGL + (size_t)QARG * QRES;        // lfunc transposed [j][r] (int)
constexpr size_t OFF_RF    = OFF_LF + (size_t)QARG * QRES;         // rfunc transposed [j][r] (int)
constexpr size_t OFF_S0    = OFF_RF + (size_t)QARG * QRES;         // split_scores[:,0] per a (256)
constexpr size_t OFF_S1    = OFF_S0 + QALL;                        // split_scores[:,1] per a (256)
constexpr size_t OFF_PM    = OFF_S1 + QALL;                        // emit partial max [wt][a]
constexpr size_t OFF_PS    = OFF_PM + (size_t)NWT * QALL;          // emit partial sum [wt][a]
constexpr size_t OFF_LSE   = OFF_PS + (size_t)NWT * QALL;          // emit row lse (256)
constexpr size_t OFF_M     = OFF_LSE + QALL;                       // m[s][b] (16*8)
constexpr size_t OFF_PART  = OFF_M + (size_t)T_ * B_;              // partial sums [sb][sub][r] (16*8*4*128)
// total ~729k floats ~ 2.92 MB

__device__ __forceinline__ size_t chIdx(int ell, int s, int b) {
    return OFF_CHART + ((size_t)((ell * 16 + s) * 8 + b)) * 256;
}

__device__ __forceinline__ float waveMax(float v) {
    #pragma unroll
    for (int m = 32; m >= 1; m >>= 1) v = fmaxf(v, __shfl_xor(v, m, 64));
    return v;
}
__device__ __forceinline__ float waveSum(float v) {
    #pragma unroll
    for (int m = 32; m >= 1; m >>= 1) v += __shfl_xor(v, m, 64);
    return v;
}
// all-threads block reductions (uniform call). trailing sync protects scratch reuse.
__device__ __forceinline__ float blockMax(float v, float* scr, int nw) {
    int lane = threadIdx.x & 63, w = threadIdx.x >> 6;
    v = waveMax(v);
    if (lane == 0) scr[w] = v;
    __syncthreads();
    float r = scr[0];
    for (int i = 1; i < nw; i++) r = fmaxf(r, scr[i]);
    __syncthreads();
    return r;
}
__device__ __forceinline__ float blockSum(float v, float* scr, int nw) {
    int lane = threadIdx.x & 63, w = threadIdx.x >> 6;
    v = waveSum(v);
    if (lane == 0) scr[w] = v;
    __syncthreads();
    float r = 0.f;
    for (int i = 0; i < nw; i++) r += scr[i];
    __syncthreads();
    return r;
}

// ---------------- G tables: log_softmax(rule_W+rule_b) + assoc, exp'd + transposed ----------------
__global__ __launch_bounds__(192) void prep_g_kernel(
        const float* __restrict__ rule_W, const float* __restrict__ rule_b,
        const float* __restrict__ assoc,
        const float* __restrict__ larg_mask, const float* __restrict__ rarg_mask,
        const int* __restrict__ lfunc, const int* __restrict__ rfunc,
        float* __restrict__ ws) {
    __shared__ float scr[4];
    int r = blockIdx.x;      // 0..127
    int j = threadIdx.x;     // 0..191
    float v0 = rule_W[r * 2 * QARG + j] + rule_b[j];
    float v1 = rule_W[r * 2 * QARG + QARG + j] + rule_b[QARG + j];
    float m = blockMax(fmaxf(v0, v1), scr, 3);
    float s = blockSum(expf(v0 - m) + expf(v1 - m), scr, 3);
    float l = m + logf(s);
    float av = assoc[r * QARG + j];
    float gl = v0 - l + av + larg_mask[r * QARG + j];
    float gr = v1 - l + av + rarg_mask[r * QARG + j];
    ws[OFF_EGL + (size_t)j * QRES + r] = expf(gl);
    ws[OFF_EGR + (size_t)j * QRES + r] = expf(gr);
    ((int*)ws)[OFF_LF + (size_t)j * QRES + r] = lfunc[r * QARG + j];
    ((int*)ws)[OFF_RF + (size_t)j * QRES + r] = rfunc[r * QARG + j];
}

// ---------------- split-score MLP: h=nt@sw1+sb1; 2 residual blocks; log_softmax(h@sw2+sb2) ----------------
// Restructured for latency hiding: 1024 threads/block (16 waves/CU instead of 4),
// split-K over 4 groups of 64 reduction elements each, unroll-16 inner loop
// (~16 loads in flight/thread). Weights are L2-resident; this is a pure MLP/TLP fix.
#define MLP_MATVEC(INBUF, W, RES) do {                                          \
    float acc_ = 0.f;                                                           \
    _Pragma("unroll 16")                                                        \
    for (int s_ = 0; s_ < 64; s_++)                                             \
        acc_ += INBUF[s0 + s_] * W[(s0 + s_) * STATE + col];                    \
    part[t] = acc_;                                                             \
    __syncthreads();                                                            \
    RES = part[col] + part[STATE + col] + part[2 * STATE + col]                 \
        + part[3 * STATE + col];                                                \
} while (0)

__global__ __launch_bounds__(1024) void mlp_kernel(
        const float* __restrict__ nt_emb,
        const float* __restrict__ sw1, const float* __restrict__ sb1,
        const float* __restrict__ r1w1, const float* __restrict__ r1b1,
        const float* __restrict__ r1w2, const float* __restrict__ r1b2,
        const float* __restrict__ r2w1, const float* __restrict__ r2b1,
        const float* __restrict__ r2w2, const float* __restrict__ r2b2,
        const float* __restrict__ sw2, const float* __restrict__ sb2,
        float* __restrict__ ws) {
    __shared__ float xin[STATE], hbuf[STATE], tbuf[STATE];
    __shared__ float part[4 * STATE];
    __shared__ float scr[16];
    int a = blockIdx.x, t = threadIdx.x;
    int col = t & 255;
    int grp = t >> 8;        // 0..3
    int s0 = grp * 64;       // this group's K-range
    if (t < STATE) xin[t] = nt_emb[a * STATE + t];
    __syncthreads();
    float r;
    // h = x @ sw1 + sb1
    MLP_MATVEC(xin, sw1, r);
    if (grp == 0) hbuf[col] = r + sb1[col];
    __syncthreads();
    // residual block 1
    MLP_MATVEC(hbuf, r1w1, r);
    if (grp == 0) tbuf[col] = fmaxf(r + r1b1[col], 0.f);
    __syncthreads();
    MLP_MATVEC(tbuf, r1w2, r);
    if (grp == 0) hbuf[col] += fmaxf(r + r1b2[col], 0.f);
    __syncthreads();
    // residual block 2
    MLP_MATVEC(hbuf, r2w1, r);
    if (grp == 0) tbuf[col] = fmaxf(r + r2b1[col], 0.f);
    __syncthreads();
    MLP_MATVEC(tbuf, r2w2, r);
    if (grp == 0) hbuf[col] += fmaxf(r + r2b2[col], 0.f);
    __syncthreads();
    // head: u0,u1 = h @ sw2 + sb2 ; log_softmax over 2
    float hv = (t < STATE) ? hbuf[t] : 0.f;
    float v0 = (t < STATE) ? hv * sw2[t * 2 + 0] : 0.f;
    float v1 = (t < STATE) ? hv * sw2[t * 2 + 1] : 0.f;
    float u0 = blockSum(v0, scr, 16) + sb2[0];
    float u1 = blockSum(v1, scr, 16) + sb2[1];
    if (t == 0) {
        float mm = fmaxf(u0, u1);
        float l = mm + logf(expf(u0 - mm) + expf(u1 - mm));
        ws[OFF_S0 + a] = u0 - l;
        ws[OFF_S1 + a] = u1 - l;
    }
}

// ---------------- emit GEMM (per-tile) with fused partial row-logsumexp ----------------
__global__ __launch_bounds__(256) void emit_kernel(
        const float* __restrict__ nt_emb, const float* __restrict__ W_emit,
        const float* __restrict__ b_emit, float* __restrict__ ws) {
    __shared__ float As[16][64];        // [kk][aa]
    __shared__ float Bs[16][128];       // [kk][ww]
    __shared__ float redM[64][16], redS[64][16];
    int wt = blockIdx.x, at = blockIdx.y;
    int t = threadIdx.x;
    int tx = t & 15, ty = t >> 4;
    float acc[4][8];
    #pragma unroll
    for (int i = 0; i < 4; i++)
        #pragma unroll
        for (int j = 0; j < 8; j++) acc[i][j] = 0.f;
    int wbase = wt * WT, abase = at * 64;
    for (int k0 = 0; k0 < STATE; k0 += 16) {
        { // stage A: 4 floats/thread (float4), store transposed to [kk][aa]
            int idx = t * 4;
            int kk = idx & 15, aa = idx >> 4;
            float4 v = *(const float4*)&nt_emb[(abase + aa) * STATE + k0 + kk];
            As[kk + 0][aa] = v.x; As[kk + 1][aa] = v.y; As[kk + 2][aa] = v.z; As[kk + 3][aa] = v.w;
        }
        { // stage B: 8 floats/thread
            int idx = t * 8;
            int kk = idx >> 7, ww = idx & 127;
            int w = wbase + ww;
            const float* src = &W_emit[(k0 + kk) * VOCAB + w];
            float4 v0, v1;
            if (w + 7 < VOCAB) {
                v0 = *(const float4*)src;
                v1 = *(const float4*)(src + 4);
            } else {
                float tv[8];
                #pragma unroll
                for (int q = 0; q < 8; q++) tv[q] = (w + q < VOCAB) ? src[q] : 0.f;
                v0 = make_float4(tv[0], tv[1], tv[2], tv[3]);
                v1 = make_float4(tv[4], tv[5], tv[6], tv[7]);
            }
            float* dst = &Bs[kk][ww];
            ((float4*)dst)[0] = v0;
            ((float4*)dst)[1] = v1;
        }
        __syncthreads();
        #pragma unroll
        for (int kk = 0; kk < 16; kk++) {
            float a4[4], b8[8];
            #pragma unroll
            for (int i = 0; i < 4; i++) a4[i] = As[kk][ty * 4 + i];
            #pragma unroll
            for (int j = 0; j < 8; j++) b8[j] = Bs[kk][tx * 8 + j];
            #pragma unroll
            for (int i = 0; i < 4; i++)
                #pragma unroll
                for (int j = 0; j < 8; j++) acc[i][j] += a4[i] * b8[j];
        }
        __syncthreads();
    }
    // epilogue: + b_emit, per-row partial (max,sumexp) over the 128 w of this tile
    float be[8];
    #pragma unroll
    for (int j = 0; j < 8; j++) {
        int w = wbase + tx * 8 + j;
        be[j] = (w < VOCAB) ? b_emit[w] : 0.f;
    }
    #pragma unroll
    for (int i = 0; i < 4; i++) {
        float mloc = -3.0e38f;
        #pragma unroll
        for (int j = 0; j < 8; j++) {
            int w = wbase + tx * 8 + j;
            if (w < VOCAB) {
                float v = acc[i][j] + be[j];
                acc[i][j] = v;
                mloc = fmaxf(mloc, v);
            }
        }
        float sloc = 0.f;
        #pragma unroll
        for (int j = 0; j < 8; j++) {
            int w = wbase + tx * 8 + j;
            if (w < VOCAB) sloc += expf(acc[i][j] - mloc);
        }
        redM[ty * 4 + i][tx] = mloc;
        redS[ty * 4 + i][tx] = sloc;
    }
    __syncthreads();
    if (t < 64) {
        float M = -3.0e38f;
        #pragma unroll
        for (int i = 0; i < 16; i++) M = fmaxf(M, redM[t][i]);
        float S = 0.f;
        #pragma unroll
        for (int i = 0; i < 16; i++) S += redS[t][i] * expf(redM[t][i] - M);
        ws[OFF_PM + (size_t)wt * QALL + abase + t] = M;
        ws[OFF_PS + (size_t)wt * QALL + abase + t] = S;
    }
}

// ---------------- combine emit partials -> lse per row ----------------
__global__ __launch_bounds__(256) void lse_kernel(float* __restrict__ ws) {
    int a = threadIdx.x;
    float M = -3.0e38f;
    for (int wt = 0; wt < NWT; wt++) M = fmaxf(M, ws[OFF_PM + (size_t)wt * QALL + a]);
    float S = 0.f;
    for (int wt = 0; wt < NWT; wt++)
        S += ws[OFF_PS + (size_t)wt * QALL + a] * expf(ws[OFF_PM + (size_t)wt * QALL + a] - M);
    ws[OFF_LSE + a] = M + logf(S);
}

// ---------------- chart level 0: emit_lp[a, words[b,t]] + split1[a] ----------------
__global__ __launch_bounds__(256) void chart0_kernel(
        const int* __restrict__ words, const float* __restrict__ nt_emb,
        const float* __restrict__ W_emit, const float* __restrict__ b_emit,
        float* __restrict__ ws) {
    int blk = blockIdx.x;            // b*16 + tp
    int b = blk >> 4, tp = blk & 15;
    int a = threadIdx.x;
    int w = words[b * T_ + tp];
    const float* arow = &nt_emb[a * STATE];
    float acc = 0.f;
    #pragma unroll 8
    for (int s = 0; s < STATE; s++) acc += arow[s] * W_emit[s * VOCAB + w];
    float val = acc + b_emit[w] - ws[OFF_LSE + a] + ws[OFF_S1 + a];
    ws[chIdx(0, tp, b) + a] = val;
}

// ---------------- per-level accumulate: partial exp-sums over (k, j-range) ----------------
__global__ __launch_bounds__(256) void accum_kernel(float* __restrict__ ws,
                                                    const int* __restrict__ argpc, int ell) {
    int sb = blockIdx.x;             // s*8 + b
    int s = sb >> 3, b = sb & 7;
    int sub = blockIdx.y;            // which*2 + jhalf
    int which = sub >> 1, jhalf = sub & 1;
    int t = threadIdx.x;
    int K = ell - 1;
    __shared__ float eA[15 * 256];   // gather-side rows (exp), k-major
    __shared__ float eB[15 * QARG];  // bcast-side gathered at argpc (exp), k-major
    __shared__ float tmp[256];
    __shared__ float mA[15], mB[15];
    __shared__ float scr[4];
    __shared__ float Sred[256];
    int ap = (t < QARG) ? argpc[t] : 0;
    // phase A: load raw rows, reduce maxes, gather bcast side at argpc
    for (int kp = 0; kp < K; kp++) {
        int k = kp + 1;
        const float* Lrow = &ws[chIdx(k - 1, s, b)];
        const float* Rrow = &ws[chIdx(ell - k - 1, s + k, b)];
        const float* Arow = which ? Rrow : Lrow;   // gather side
        const float* Brow = which ? Lrow : Rrow;   // broadcast side
        float av = Arow[t];
        float bv = Brow[t];
        eA[kp * 256 + t] = av;
        tmp[t] = bv;
        float mAv = blockMax(av, scr, 4);          // internal syncs also publish tmp
        float mBv = blockMax(bv, scr, 4);
        if (t == 0) { mA[kp] = mAv; mB[kp] = mBv; }
        if (t < QARG) eB[kp * QARG + t] = tmp[ap];
        __syncthreads();                           // protect tmp before next kp
    }
    // global scale m (identical across all 4 sub-blocks: fmax is exact)
    float m = -3.0e38f;
    for (int kp = 0; kp < K; kp++) m = fmaxf(m, mA[kp] + mB[kp]);
    if (t == 0) ws[OFF_M + s * 8 + b] = m;         // duplicate identical writes: benign
    // phase B: exponentiate in place
    for (int kp = 0; kp < K; kp++) {
        float sA = mA[kp];
        eA[kp * 256 + t] = expf(eA[kp * 256 + t] - sA);
        if (t < QARG) eB[kp * QARG + t] = expf(eB[kp * QARG + t] - (m - sA));
    }
    __syncthreads();
    // phase C: acc over (j in 48-range, k): sum_j g[r,j] * sum_k eA[gatherIdx]*eB[j]
    int r = t & 127, jsub = t >> 7;
    int j0 = jhalf * 96 + jsub * 48;
    const float* eGT = ws + (which == 0 ? OFF_EGR : OFF_EGL);
    const int* idxT = ((const int*)ws) + (which == 0 ? OFF_LF : OFF_RF);
    float acc = 0.f;
    for (int jc = 0; jc < 48; jc += 4) {
        int j = j0 + jc;
        float g0 = eGT[(size_t)(j + 0) * QRES + r];
        float g1 = eGT[(size_t)(j + 1) * QRES + r];
        float g2 = eGT[(size_t)(j + 2) * QRES + r];
        float g3 = eGT[(size_t)(j + 3) * QRES + r];
        int i0 = idxT[(size_t)(j + 0) * QRES + r];
        int i1 = idxT[(size_t)(j + 1) * QRES + r];
        int i2 = idxT[(size_t)(j + 2) * QRES + r];
        int i3 = idxT[(size_t)(j + 3) * QRES + r];
        float t0 = 0.f, t1 = 0.f, t2 = 0.f, t3 = 0.f;
        for (int kp = 0; kp < K; kp++) {
            const float* gs = &eA[kp * 256];
            float4 e4 = *(const float4*)&eB[kp * QARG + j];
            t0 += gs[i0] * e4.x;
            t1 += gs[i1] * e4.y;
            t2 += gs[i2] * e4.z;
            t3 += gs[i3] * e4.w;
        }
        acc += g0 * t0 + g1 * t1 + g2 * t2 + g3 * t3;
    }
    Sred[t] = acc;
    __syncthreads();
    if (t < QRES) {
        float v = Sred[t] + Sred[QRES + t];
        ws[OFF_PART + ((size_t)sb * 4 + sub) * QRES + t] = v;
    }
}

// ---------------- per-level finalize: log(sum of 4 partials) + m + split0, write chart row ----------------
__global__ __launch_bounds__(256) void finalize_kernel(float* __restrict__ ws,
                                                       const int* __restrict__ res2all, int ell) {
    int sb = blockIdx.x;
    int s = sb >> 3, b = sb & 7;
    int t = threadIdx.x;
    __shared__ float outrow[256];
    outrow[t] = NEGV;
    __syncthreads();
    if (t < QRES) {
        const float* part = &ws[OFF_PART + (size_t)sb * 4 * QRES];
        float S = part[t] + part[QRES + t] + part[2 * QRES + t] + part[3 * QRES + t];
        float m = ws[OFF_M + s * 8 + b];
        float parent = logf(S) + m + ws[OFF_S0 + res2all[t]];
        outrow[res2all[t]] = parent;
    }
    __syncthreads();
    ws[chIdx(ell - 1, s, b) + t] = outrow[t];
}

// ---------------- root: logsumexp(chart[T-1,0,b] + log_softmax(root_w+root_b)) ----------------
__global__ __launch_bounds__(256) void root_kernel(const float* __restrict__ root_w,
                                                   const float* __restrict__ root_b,
                                                   const float* __restrict__ ws,
                                                   float* __restrict__ out) {
    int b = blockIdx.x, t = threadIdx.x;
    __shared__ float scr[4];
    float rv = root_w[t] + root_b[t];
    float mroot = blockMax(rv, scr, 4);
    float sroot = blockSum(expf(rv - mroot), scr, 4);
    float lroot = mroot + logf(sroot);
    float v = ws[chIdx(T_ - 1, 0, b) + t] + rv - lroot;
    float m2 = blockMax(v, scr, 4);
    float s2 = blockSum(expf(v - m2), scr, 4);
    if (t == 0) out[b] = m2 + logf(s2);
}

extern "C" void kernel_launch(void* const* d_in, const int* in_sizes, int n_in,
                              void* d_out, int out_size, void* d_ws, size_t ws_size,
                              hipStream_t stream) {
    const int*   words   = (const int*)  d_in[0];
    const float* nt_emb  = (const float*)d_in[1];
    const float* W_emit  = (const float*)d_in[2];
    const float* b_emit  = (const float*)d_in[3];
    const float* rule_W  = (const float*)d_in[4];
    const float* rule_b  = (const float*)d_in[5];
    const float* assoc   = (const float*)d_in[6];
    const float* root_w  = (const float*)d_in[7];
    const float* root_b  = (const float*)d_in[8];
    const float* sw1     = (const float*)d_in[9];
    const float* sb1     = (const float*)d_in[10];
    const float* r1w1    = (const float*)d_in[11];
    const float* r1b1    = (const float*)d_in[12];
    const float* r1w2    = (const float*)d_in[13];
    const float* r1b2    = (const float*)d_in[14];
    const float* r2w1    = (const float*)d_in[15];
    const float* r2b1    = (const float*)d_in[16];
    const float* r2w2    = (const float*)d_in[17];
    const float* r2b2    = (const float*)d_in[18];
    const float* sw2     = (const float*)d_in[19];
    const float* sb2     = (const float*)d_in[20];
    const int*   lfunc   = (const int*)  d_in[21];
    const int*   rfunc   = (const int*)  d_in[22];
    const int*   argpc   = (const int*)  d_in[23];
    const int*   res2all = (const int*)  d_in[24];
    const float* larg_m  = (const float*)d_in[25];
    const float* rarg_m  = (const float*)d_in[26];
    float* ws  = (float*)d_ws;
    float* out = (float*)d_out;

    prep_g_kernel<<<dim3(QRES), dim3(QARG), 0, stream>>>(rule_W, rule_b, assoc, larg_m, rarg_m,
                                                         lfunc, rfunc, ws);
    mlp_kernel<<<dim3(QALL), dim3(1024), 0, stream>>>(nt_emb, sw1, sb1, r1w1, r1b1, r1w2, r1b2,
                                                      r2w1, r2b1, r2w2, r2b2, sw2, sb2, ws);
    emit_kernel<<<dim3(NWT, QALL / 64), dim3(256), 0, stream>>>(nt_emb, W_emit, b_emit, ws);
    lse_kernel<<<dim3(1), dim3(256), 0, stream>>>(ws);
    chart0_kernel<<<dim3(B_ * T_), dim3(256), 0, stream>>>(words, nt_emb, W_emit, b_emit, ws);
    for (int ell = 2; ell <= T_; ell++) {
        int n = T_ - ell + 1;
        accum_kernel<<<dim3(n * 8, 4), dim3(256), 0, stream>>>(ws, argpc, ell);
        finalize_kernel<<<dim3(n * 8), dim3(256), 0, stream>>>(ws, res2all, ell);
    }
    root_kernel<<<dim3(B_), dim3(256), 0, stream>>>(root_w, root_b, ws, out);
}